// Round 11
// baseline (76.323 us; speedup 1.0000x reference)
//
#include <hip/hip_runtime.h>
#include <hip/hip_bf16.h>
#include <stdint.h>

#define NB  256     // batch
#define NSP 128     // n_spins
#define DM  768     // d_model
#define KMC 25      // coalitions
#define MROWS (NB*KMC)  // 6400

// workspace layout (bytes), all 256-aligned (ws is 384 MiB)
#define OFF_S    0u          // s bf16 [6400][768]          9,830,400 B
#define OFF_WT   9830400u    // w_v^T bf16 [768][768]       1,179,648 B
#define OFF_N2   11010048u   // norm2 f32 [6400]               25,600 B
#define OFF_COEF 11035648u   // coefT f32 [128][28]            14,336 B
#define OFF_CB   11049984u   // Cb bf16 [32][128] (pad rows)    8,192 B

typedef __attribute__((ext_vector_type(8))) short bf16x8;
typedef __attribute__((ext_vector_type(4))) float f32x4;
typedef unsigned int u32;

#define GLOAD_LDS16(gp, lp) \
  __builtin_amdgcn_global_load_lds((const __attribute__((address_space(1))) u32*)(gp), \
                                   (__attribute__((address_space(3))) u32*)(lp), 16, 0, 0)

// counted-vmcnt barrier (T4): wait until only the N newest VMEM ops remain.
#define KA_WAITV_BAR(N) asm volatile("s_waitcnt vmcnt(" #N ")\n\ts_barrier" ::: "memory")
// post-read barrier before a ring buffer is re-targeted by DMA
#define KA_BAR()        asm volatile("s_waitcnt lgkmcnt(0)\n\ts_barrier" ::: "memory")
// rep boundary: full drain (stores + DMA) so next rep's counted waits are exact
#define KA_REP_END()    asm volatile("s_waitcnt vmcnt(0) lgkmcnt(0)\n\ts_barrier" ::: "memory")

// ---------------- prep: transpose w_v -> bf16 wT, coef/C tables, zero norm2 -
__global__ __launch_bounds__(256) void prep_kernel(const float* __restrict__ wv,
                                                   const int* __restrict__ co,
                                                   char* __restrict__ ws) {
  const int blk = blockIdx.x;
  const int t = threadIdx.x;
  if (blk < 144) {               // 12x12 tiles of 64x64: wT[n][k] = bf16(wv[k][n])
    __shared__ __hip_bfloat16 lt[64][66];
    const int bi = blk / 12, bj = blk % 12;
    const int k0 = bi * 64, n0 = bj * 64;
    #pragma unroll
    for (int i = 0; i < 16; ++i) {
      int idx = t + i * 256;
      int r = idx >> 6, c = idx & 63;
      lt[c][r] = __float2bfloat16(wv[(size_t)(k0 + r) * DM + n0 + c]);
    }
    __syncthreads();
    __hip_bfloat16* wT = (__hip_bfloat16*)(ws + OFF_WT);
    #pragma unroll
    for (int i = 0; i < 16; ++i) {
      int idx = t + i * 256;
      int r = idx >> 6, c = idx & 63;
      wT[(size_t)(n0 + r) * DM + k0 + c] = lt[r][c];
    }
  } else if (blk == 144) {       // per-(n,k) shapley coefficients
    if (t < NSP) {
      const int n = t;
      int cw = 0;
      #pragma unroll
      for (int k = 0; k < KMC; ++k) cw += co[k * NSP + n];
      const int cwo = KMC - cw;
      const bool valid = (cw > 0) && (cwo > 0);
      float* coefT = (float*)(ws + OFF_COEF);
      #pragma unroll
      for (int k = 0; k < 28; ++k) {
        float v = 0.f;
        if (valid && k < KMC) v = co[k * NSP + n] ? (1.f / (float)cw) : (-1.f / (float)cwo);
        coefT[n * 28 + k] = v;
      }
    }
  } else if (blk < 170) {        // zero norm2 accumulators
    int i = (blk - 145) * 256 + t;
    if (i < MROWS) ((float*)(ws + OFF_N2))[i] = 0.f;
  } else {                       // blk 170..201: Cb row k (bf16, rows>=KMC zero)
    int k = blk - 170;
    if (t < NSP) {
      float v = (k < KMC) ? (float)co[k * NSP + t] : 0.f;
      ((__hip_bfloat16*)(ws + OFF_CB))[k * NSP + t] = __float2bfloat16(v);
    }
  }
}

// ---------------- kernel A: s[b] = C(25x128) x F_b(128x768) via bf16 MFMA ---
// DIAGNOSTIC BUILD: body repeated KA_REPS times inside ONE dispatch so kA's
// own counters surface in the rocprof top-5 (harness 57us fills mask shorter
// dispatches). Reps are idempotent (re-zero acc, identical stores). ALSO:
// bank-swizzle on DMA source + LDS read (col ^= (row>>3)<<3) -> fragment
// ds_read_b32 drops 4-way -> 2-way (free). Verify via SQ_LDS_BANK_CONFLICT.
#define KA_REPS 3

__global__ __launch_bounds__(256, 2) void kA(const float* __restrict__ f,
                                             const __hip_bfloat16* __restrict__ Cb,
                                             __hip_bfloat16* __restrict__ s) {
  const int b = blockIdx.x;
  const int slice = blockIdx.y;    // 4 slices x 192 cols
  const int tid = threadIdx.x;
  const int w = tid >> 6;          // 4 waves
  const int lane = tid & 63;
  const int lo = lane & 15, hi = lane >> 4;

  __shared__ __align__(16) float Fs[3][32 * 192];   // 73,728 B ring

  // A-fragments (coalition rows), k = ks*32 + hi*8 + j (proven mapping)
  bf16x8 A0[4], A1[4];
  #pragma unroll
  for (int ks = 0; ks < 4; ++ks) {
    A0[ks] = *(const bf16x8*)(Cb + (size_t)lo * NSP + ks * 32 + hi * 8);
    A1[ks] = *(const bf16x8*)(Cb + (size_t)(16 + lo) * NSP + ks * 32 + hi * 8);
  }

  // DMA geometry with bank swizzle: LDS slot (row,c) receives f(row, c^swz(row)),
  // swz(row) = ((row>>3)&3)<<3 (multiples of 8 floats = 32B; each lane's 16B
  // slot stays contiguous). Read side XORs the same -> involution (rule #21).
  int goff[6];
  #pragma unroll
  for (int q = 0; q < 6; ++q) {
    int e = (w * 6 + q) * 256 + lane * 4;
    int r = e / 192, c = e - r * 192;
    int csw = c ^ (((r >> 3) & 3) << 3);
    goff[q] = r * DM + csw;
  }

  const float* fb = f + (size_t)b * NSP * DM + slice * 192;

  f32x4 ac0[3], ac1[3];

#define KA_ISSUE(ck, bi) { \
    const float* fp_ = fb + (size_t)(ck) * 32 * DM; \
    _Pragma("unroll") for (int q = 0; q < 6; ++q) \
      GLOAD_LDS16(fp_ + goff[q], (char*)&Fs[(bi)][0] + ((w * 6 + q) << 10)); }

#define KA_MFMA(ck, bi) { \
    _Pragma("unroll") for (int ct = 0; ct < 3; ++ct) { \
      bf16x8 Bf; \
      _Pragma("unroll") for (int j = 0; j < 8; ++j) { \
        float v_ = Fs[(bi)][(hi * 8 + j) * 192 + ((w * 48 + ct * 16 + lo) ^ (hi << 3))]; \
        __hip_bfloat16 h_ = __float2bfloat16(v_); \
        Bf[j] = *(short*)&h_; } \
      ac0[ct] = __builtin_amdgcn_mfma_f32_16x16x32_bf16(A0[ck], Bf, ac0[ct], 0, 0, 0); \
      ac1[ct] = __builtin_amdgcn_mfma_f32_16x16x32_bf16(A1[ck], Bf, ac1[ct], 0, 0, 0); } }

  for (int rep = 0; rep < KA_REPS; ++rep) {
    #pragma unroll
    for (int ct = 0; ct < 3; ++ct)
      #pragma unroll
      for (int i = 0; i < 4; ++i) { ac0[ct][i] = 0.f; ac1[ct][i] = 0.f; }

    KA_ISSUE(0, 0)                 // 6 DMA/wave
    KA_ISSUE(1, 1)                 // 12
    KA_ISSUE(2, 2)                 // 18 in flight
    KA_WAITV_BAR(12);              // chunk0 landed (keep newest 12: c1,c2)
    KA_MFMA(0, 0)
    KA_BAR();                      // all waves done reading buf0 -> re-DMA safe
    KA_ISSUE(3, 0)
    KA_WAITV_BAR(12);              // chunk1 landed (keep c2,c3)
    KA_MFMA(1, 1)
    KA_WAITV_BAR(6);               // chunk2 landed (keep c3)
    KA_MFMA(2, 2)
    KA_WAITV_BAR(0);               // chunk3 landed
    KA_MFMA(3, 0)

    // epilogue: D layout col=lane&15, row=(lane>>4)*4+i (idempotent per rep)
    #pragma unroll
    for (int ct = 0; ct < 3; ++ct) {
      int dcol = slice * 192 + w * 48 + ct * 16 + lo;
      #pragma unroll
      for (int i = 0; i < 4; ++i) {
        int r0 = hi * 4 + i;
        s[((size_t)b * KMC + r0) * DM + dcol] = __float2bfloat16(ac0[ct][i]);
        int r1 = 16 + hi * 4 + i;
        if (r1 < KMC)
          s[((size_t)b * KMC + r1) * DM + dcol] = __float2bfloat16(ac1[ct][i]);
      }
    }
    KA_REP_END();                  // drain stores+DMA: next rep's counts exact
  }

#undef KA_ISSUE
#undef KA_MFMA
}

// ---------------- kernel B: norm2[row] += rowwise |s @ wT^T|^2 (bf16 MFMA) ---
#define BM 128
#define BN 192
#define BK 32
#define NTK 24   // 768/32

__global__ __launch_bounds__(256) void kB(char* __restrict__ ws) {
  const int bid = blockIdx.x;      // grid 200 = 50 (M) * 4 (N)
  const int tm = bid >> 2;
  const int tn = bid & 3;
  const int tid = threadIdx.x;
  const int wid = tid >> 6;
  const int lane = tid & 63;
  const int wm = wid >> 1;         // 2x2 wave grid: 64 rows x 96 cols per wave
  const int wn = wid & 1;

  const __hip_bfloat16* S  = (const __hip_bfloat16*)(ws + OFF_S);
  const __hip_bfloat16* WT = (const __hip_bfloat16*)(ws + OFF_WT);
  float* norm2 = (float*)(ws + OFF_N2);

  __shared__ __align__(16) char As[2][BM * BK * 2];  // [128][32] bf16, 64B rows
  __shared__ __align__(16) char Bs[2][BN * BK * 2];  // [192][32] bf16, 64B rows

  // staging: global src pre-swizzled (slot ^= (r>>1)&3), LDS dest linear
  const char* gA[2]; char *lA0[2], *lA1[2];
  #pragma unroll
  for (int j = 0; j < 2; ++j) {
    int li = (wid * 2 + j) * 64 + lane;
    int r = li >> 2, sl = li & 3;
    int slx = sl ^ ((r >> 1) & 3);
    gA[j] = (const char*)(S + (size_t)(tm * BM + r) * DM) + slx * 16;
    lA0[j] = As[0] + (wid * 2 + j) * 1024;
    lA1[j] = As[1] + (wid * 2 + j) * 1024;
  }
  const char* gB[3]; char *lB0[3], *lB1[3];
  #pragma unroll
  for (int j = 0; j < 3; ++j) {
    int li = (wid * 3 + j) * 64 + lane;
    int r = li >> 2, sl = li & 3;
    int slx = sl ^ ((r >> 1) & 3);
    gB[j] = (const char*)(WT + (size_t)(tn * BN + r) * DM) + slx * 16;
    lB0[j] = Bs[0] + (wid * 3 + j) * 1024;
    lB1[j] = Bs[1] + (wid * 3 + j) * 1024;
  }

  auto stage = [&](int tk, int bsel) {
    size_t koff = (size_t)tk * (BK * 2);   // 64 bytes per K-step
    #pragma unroll
    for (int j = 0; j < 2; ++j) GLOAD_LDS16(gA[j] + koff, bsel ? lA1[j] : lA0[j]);
    #pragma unroll
    for (int j = 0; j < 3; ++j) GLOAD_LDS16(gB[j] + koff, bsel ? lB1[j] : lB0[j]);
  };

  f32x4 acc[4][6];
  #pragma unroll
  for (int m = 0; m < 4; ++m)
    #pragma unroll
    for (int n = 0; n < 6; ++n)
      #pragma unroll
      for (int j = 0; j < 4; ++j) acc[m][n][j] = 0.f;

  // fragment read offsets (swizzled to match stage-source permutation)
  int offA[4], offB[6];
  #pragma unroll
  for (int m = 0; m < 4; ++m) {
    int r = wm * 64 + m * 16 + (lane & 15);
    int sl = (lane >> 4) ^ ((r >> 1) & 3);
    offA[m] = r * 64 + sl * 16;
  }
  #pragma unroll
  for (int n = 0; n < 6; ++n) {
    int r = wn * 96 + n * 16 + (lane & 15);
    int sl = (lane >> 4) ^ ((r >> 1) & 3);
    offB[n] = r * 64 + sl * 16;
  }

  stage(0, 0);
  for (int tk = 0; tk < NTK; ++tk) {
    int cur = tk & 1;
    __syncthreads();               // drains vmcnt(0): staged tile ready
    if (tk + 1 < NTK) stage(tk + 1, cur ^ 1);
    bf16x8 af[4], bfr[6];
    #pragma unroll
    for (int m = 0; m < 4; ++m) af[m] = *(const bf16x8*)(As[cur] + offA[m]);
    #pragma unroll
    for (int n = 0; n < 6; ++n) bfr[n] = *(const bf16x8*)(Bs[cur] + offB[n]);
    #pragma unroll
    for (int m = 0; m < 4; ++m)
      #pragma unroll
      for (int n = 0; n < 6; ++n)
        acc[m][n] = __builtin_amdgcn_mfma_f32_16x16x32_bf16(af[m], bfr[n], acc[m][n], 0, 0, 0);
  }

  // epilogue: sum of squares over this block's 96-col slice, reduce 16 lanes,
  // atomicAdd into norm2[row]  (C/D layout: col=lane&15, row=(lane>>4)*4+reg)
  float ps[4][4];
  #pragma unroll
  for (int m = 0; m < 4; ++m)
    #pragma unroll
    for (int i = 0; i < 4; ++i) {
      float v = 0.f;
      #pragma unroll
      for (int n = 0; n < 6; ++n) { float x = acc[m][n][i]; v += x * x; }
      #pragma unroll
      for (int d = 1; d < 16; d <<= 1) v += __shfl_xor(v, d, 64);
      ps[m][i] = v;
    }
  if ((lane & 15) == 0) {
    int g = lane >> 4;
    #pragma unroll
    for (int m = 0; m < 4; ++m)
      #pragma unroll
      for (int i = 0; i < 4; ++i)
        atomicAdd(&norm2[tm * BM + wm * 64 + m * 16 + g * 4 + i], ps[m][i]);
  }
}

// ---------------- kernel C: cv = relu(sqrt(norm2)*scale); shapley ------------
__global__ __launch_bounds__(128) void kC(const char* __restrict__ ws,
                                          const float* __restrict__ scale,
                                          float* __restrict__ out) {
  const int b = blockIdx.x, n = threadIdx.x;
  const float* norm2 = (const float*)(ws + OFF_N2);
  const float* coefT = (const float*)(ws + OFF_COEF);
  __shared__ float cvs[32];
  if (n < KMC) {
    float nv = norm2[b * KMC + n];
    cvs[n] = fmaxf(sqrtf(fmaxf(nv, 0.f)) * scale[0], 0.f);
  } else if (n < 32) {
    cvs[n] = 0.f;
  }
  __syncthreads();
  float sum = 0.f;
  #pragma unroll
  for (int k = 0; k < KMC; ++k) sum += cvs[k] * coefT[n * 28 + k];
  out[b * NSP + n] = sum;
}

extern "C" void kernel_launch(void* const* d_in, const int* in_sizes, int n_in,
                              void* d_out, int out_size, void* d_ws, size_t ws_size,
                              hipStream_t stream) {
  const float* features   = (const float*)d_in[0];
  const int*   coalitions = (const int*)d_in[1];
  const float* wv         = (const float*)d_in[2];
  const float* scale      = (const float*)d_in[3];
  char* ws = (char*)d_ws;

  prep_kernel<<<202, 256, 0, stream>>>(wv, coalitions, ws);
  dim3 gaa(NB, 4);
  kA<<<gaa, 256, 0, stream>>>(features, (const __hip_bfloat16*)(ws + OFF_CB),
                              (__hip_bfloat16*)(ws + OFF_S));
  kB<<<200, 256, 0, stream>>>(ws);
  kC<<<NB, 128, 0, stream>>>(ws, scale, (float*)d_out);
}

// Round 12
// 51.788 us; speedup vs baseline: 1.4738x; 1.4738x over previous
//
#include <hip/hip_runtime.h>
#include <hip/hip_bf16.h>
#include <stdint.h>

#define NB  256     // batch
#define NSP 128     // n_spins
#define DM  768     // d_model
#define KMC 25      // coalitions
#define MROWS (NB*KMC)  // 6400

// workspace layout (bytes), all 256-aligned (ws is 384 MiB)
#define OFF_S    0u          // s bf16 [6400][768]          9,830,400 B
#define OFF_WT   9830400u    // w_v^T bf16 [768][768]       1,179,648 B
#define OFF_N2   11010048u   // norm2 f32 [6400]               25,600 B
#define OFF_COEF 11035648u   // coefT f32 [128][28]            14,336 B
#define OFF_CB   11049984u   // Cb bf16 [32][128] (pad rows)    8,192 B

typedef __attribute__((ext_vector_type(8))) short bf16x8;
typedef __attribute__((ext_vector_type(4))) float f32x4;
typedef unsigned int u32;

#define GLOAD_LDS16(gp, lp) \
  __builtin_amdgcn_global_load_lds((const __attribute__((address_space(1))) u32*)(gp), \
                                   (__attribute__((address_space(3))) u32*)(lp), 16, 0, 0)

// counted-vmcnt barrier (T4): wait until only the N newest VMEM ops remain.
#define KA_WAITV_BAR(N) asm volatile("s_waitcnt vmcnt(" #N ")\n\ts_barrier" ::: "memory")
// post-read barrier (LDS reads done) before ring buffers are re-targeted
#define KA_BAR()        asm volatile("s_waitcnt lgkmcnt(0)\n\ts_barrier" ::: "memory")

// ---------------- prep: transpose w_v -> bf16 wT, coef/C tables, zero norm2 -
__global__ __launch_bounds__(256) void prep_kernel(const float* __restrict__ wv,
                                                   const int* __restrict__ co,
                                                   char* __restrict__ ws) {
  const int blk = blockIdx.x;
  const int t = threadIdx.x;
  if (blk < 144) {               // 12x12 tiles of 64x64: wT[n][k] = bf16(wv[k][n])
    __shared__ __hip_bfloat16 lt[64][66];
    const int bi = blk / 12, bj = blk % 12;
    const int k0 = bi * 64, n0 = bj * 64;
    #pragma unroll
    for (int i = 0; i < 16; ++i) {
      int idx = t + i * 256;
      int r = idx >> 6, c = idx & 63;
      lt[c][r] = __float2bfloat16(wv[(size_t)(k0 + r) * DM + n0 + c]);
    }
    __syncthreads();
    __hip_bfloat16* wT = (__hip_bfloat16*)(ws + OFF_WT);
    #pragma unroll
    for (int i = 0; i < 16; ++i) {
      int idx = t + i * 256;
      int r = idx >> 6, c = idx & 63;
      wT[(size_t)(n0 + r) * DM + k0 + c] = lt[r][c];
    }
  } else if (blk == 144) {       // per-(n,k) shapley coefficients
    if (t < NSP) {
      const int n = t;
      int cw = 0;
      #pragma unroll
      for (int k = 0; k < KMC; ++k) cw += co[k * NSP + n];
      const int cwo = KMC - cw;
      const bool valid = (cw > 0) && (cwo > 0);
      float* coefT = (float*)(ws + OFF_COEF);
      #pragma unroll
      for (int k = 0; k < 28; ++k) {
        float v = 0.f;
        if (valid && k < KMC) v = co[k * NSP + n] ? (1.f / (float)cw) : (-1.f / (float)cwo);
        coefT[n * 28 + k] = v;
      }
    }
  } else if (blk < 170) {        // zero norm2 accumulators
    int i = (blk - 145) * 256 + t;
    if (i < MROWS) ((float*)(ws + OFF_N2))[i] = 0.f;
  } else {                       // blk 170..201: Cb row k (bf16, rows>=KMC zero)
    int k = blk - 170;
    if (t < NSP) {
      float v = (k < KMC) ? (float)co[k * NSP + t] : 0.f;
      ((__hip_bfloat16*)(ws + OFF_CB))[k * NSP + t] = __float2bfloat16(v);
    }
  }
}

// ---------------- kernel A: s[b] = C(25x128) x F_b(128x768) via bf16 MFMA ---
// v7: deep + undrained + occupied (r11 counters: all pipes idle -> latency-
// bound; need ~53KB in flight/CU). 16-row chunks (12KB), ring-4 = 48KB LDS
// -> 3 blocks/CU = 12 waves/CU. 8 chunks/block; counted vmcnt(6..0); only 6
// barriers; MFMA consumes chunk PAIRS with the proven 16x16x32 intrinsic
// (B row = (hi&1)*8+j, buffer chosen by hi>>1). Steady 6-12 DMA/wave in
// flight -> 72-144 KB/CU outstanding.
__global__ __launch_bounds__(256, 3) void kA(const float* __restrict__ f,
                                             const __hip_bfloat16* __restrict__ Cb,
                                             __hip_bfloat16* __restrict__ s) {
  const int b = blockIdx.x;
  const int slice = blockIdx.y;    // 4 slices x 192 cols
  const int tid = threadIdx.x;
  const int w = tid >> 6;          // 4 waves
  const int lane = tid & 63;
  const int lo = lane & 15, hi = lane >> 4;

  __shared__ __align__(16) float Fs[4][16 * 192];   // 49,152 B ring (4 x 12KB)

  // A-fragments (coalition rows), k = ks*32 + hi*8 + j (proven mapping)
  bf16x8 A0[4], A1[4];
  #pragma unroll
  for (int ks = 0; ks < 4; ++ks) {
    A0[ks] = *(const bf16x8*)(Cb + (size_t)lo * NSP + ks * 32 + hi * 8);
    A1[ks] = *(const bf16x8*)(Cb + (size_t)(16 + lo) * NSP + ks * 32 + hi * 8);
  }
  asm volatile("s_waitcnt vmcnt(0)" ::: "memory");   // clean vmcnt base

  // DMA geometry: chunk = 16 rows x 192 cols f32. Wave w stages windows
  // w*3..w*3+2 (1024B each). Window q: float e=(w*3+q)*256+lane*4 -> r=e/192,
  // c=e%192 (4|c, 16B never crosses row end). Per-lane GLOBAL src; LDS dest
  // wave-uniform + lane*16 (linear).
  int goff[3];
  #pragma unroll
  for (int q = 0; q < 3; ++q) {
    int e = (w * 3 + q) * 256 + lane * 4;
    int r = e / 192, c = e - r * 192;
    goff[q] = r * DM + c;
  }

  const float* fb = f + (size_t)b * NSP * DM + slice * 192;

  f32x4 ac0[3], ac1[3];
  #pragma unroll
  for (int ct = 0; ct < 3; ++ct)
    #pragma unroll
    for (int i = 0; i < 4; ++i) { ac0[ct][i] = 0.f; ac1[ct][i] = 0.f; }

#define KA_ISSUE(ck, bi) { \
    const float* fp_ = fb + (size_t)(ck) * 16 * DM; \
    _Pragma("unroll") for (int q = 0; q < 3; ++q) \
      GLOAD_LDS16(fp_ + goff[q], (char*)&Fs[(bi)][0] + ((w * 3 + q) << 10)); }

  // MFMA over chunk pair (blo = k rows 0-15, bhi = k rows 16-31):
  // lane k = hi*8+j -> buffer (hi>>1 ? bhi : blo), row (hi&1)*8+j.
#define KA_MFMAPAIR(ks, blo, bhi) { \
    const float* Fb_ = (hi >> 1) ? &Fs[(bhi)][0] : &Fs[(blo)][0]; \
    const int rb_ = (hi & 1) * 8; \
    _Pragma("unroll") for (int ct = 0; ct < 3; ++ct) { \
      bf16x8 Bf; \
      _Pragma("unroll") for (int j = 0; j < 8; ++j) { \
        float v_ = Fb_[(rb_ + j) * 192 + w * 48 + ct * 16 + lo]; \
        __hip_bfloat16 h_ = __float2bfloat16(v_); \
        Bf[j] = *(short*)&h_; } \
      ac0[ct] = __builtin_amdgcn_mfma_f32_16x16x32_bf16(A0[ks], Bf, ac0[ct], 0, 0, 0); \
      ac1[ct] = __builtin_amdgcn_mfma_f32_16x16x32_bf16(A1[ks], Bf, ac1[ct], 0, 0, 0); } }

  KA_ISSUE(0, 0) KA_ISSUE(1, 1) KA_ISSUE(2, 2) KA_ISSUE(3, 3)  // 12 DMA/wave
  KA_WAITV_BAR(6);               // c0,c1 landed (keep newest 6 = c2,c3)
  KA_MFMAPAIR(0, 0, 1)
  KA_BAR();                      // all waves done with bufs 0,1
  KA_ISSUE(4, 0) KA_ISSUE(5, 1)  // back to 12 in flight
  KA_WAITV_BAR(6);               // c2,c3 landed (keep c4,c5)
  KA_MFMAPAIR(1, 2, 3)
  KA_BAR();                      // bufs 2,3 free
  KA_ISSUE(6, 2) KA_ISSUE(7, 3)
  KA_WAITV_BAR(6);               // c4,c5 landed (keep c6,c7)
  KA_MFMAPAIR(2, 0, 1)
  KA_WAITV_BAR(0);               // c6,c7 landed
  KA_MFMAPAIR(3, 2, 3)

#undef KA_ISSUE
#undef KA_MFMAPAIR

  // epilogue: D layout col=lane&15, row=(lane>>4)*4+i
  #pragma unroll
  for (int ct = 0; ct < 3; ++ct) {
    int dcol = slice * 192 + w * 48 + ct * 16 + lo;
    #pragma unroll
    for (int i = 0; i < 4; ++i) {
      int r0 = hi * 4 + i;
      s[((size_t)b * KMC + r0) * DM + dcol] = __float2bfloat16(ac0[ct][i]);
      int r1 = 16 + hi * 4 + i;
      if (r1 < KMC)
        s[((size_t)b * KMC + r1) * DM + dcol] = __float2bfloat16(ac1[ct][i]);
    }
  }
}

// ---------------- kernel B: norm2[row] += rowwise |s @ wT^T|^2 (bf16 MFMA) ---
#define BM 128
#define BN 192
#define BK 32
#define NTK 24   // 768/32

__global__ __launch_bounds__(256) void kB(char* __restrict__ ws) {
  const int bid = blockIdx.x;      // grid 200 = 50 (M) * 4 (N)
  const int tm = bid >> 2;
  const int tn = bid & 3;
  const int tid = threadIdx.x;
  const int wid = tid >> 6;
  const int lane = tid & 63;
  const int wm = wid >> 1;         // 2x2 wave grid: 64 rows x 96 cols per wave
  const int wn = wid & 1;

  const __hip_bfloat16* S  = (const __hip_bfloat16*)(ws + OFF_S);
  const __hip_bfloat16* WT = (const __hip_bfloat16*)(ws + OFF_WT);
  float* norm2 = (float*)(ws + OFF_N2);

  __shared__ __align__(16) char As[2][BM * BK * 2];  // [128][32] bf16, 64B rows
  __shared__ __align__(16) char Bs[2][BN * BK * 2];  // [192][32] bf16, 64B rows

  // staging: global src pre-swizzled (slot ^= (r>>1)&3), LDS dest linear
  const char* gA[2]; char *lA0[2], *lA1[2];
  #pragma unroll
  for (int j = 0; j < 2; ++j) {
    int li = (wid * 2 + j) * 64 + lane;
    int r = li >> 2, sl = li & 3;
    int slx = sl ^ ((r >> 1) & 3);
    gA[j] = (const char*)(S + (size_t)(tm * BM + r) * DM) + slx * 16;
    lA0[j] = As[0] + (wid * 2 + j) * 1024;
    lA1[j] = As[1] + (wid * 2 + j) * 1024;
  }
  const char* gB[3]; char *lB0[3], *lB1[3];
  #pragma unroll
  for (int j = 0; j < 3; ++j) {
    int li = (wid * 3 + j) * 64 + lane;
    int r = li >> 2, sl = li & 3;
    int slx = sl ^ ((r >> 1) & 3);
    gB[j] = (const char*)(WT + (size_t)(tn * BN + r) * DM) + slx * 16;
    lB0[j] = Bs[0] + (wid * 3 + j) * 1024;
    lB1[j] = Bs[1] + (wid * 3 + j) * 1024;
  }

  auto stage = [&](int tk, int bsel) {
    size_t koff = (size_t)tk * (BK * 2);   // 64 bytes per K-step
    #pragma unroll
    for (int j = 0; j < 2; ++j) GLOAD_LDS16(gA[j] + koff, bsel ? lA1[j] : lA0[j]);
    #pragma unroll
    for (int j = 0; j < 3; ++j) GLOAD_LDS16(gB[j] + koff, bsel ? lB1[j] : lB0[j]);
  };

  f32x4 acc[4][6];
  #pragma unroll
  for (int m = 0; m < 4; ++m)
    #pragma unroll
    for (int n = 0; n < 6; ++n)
      #pragma unroll
      for (int j = 0; j < 4; ++j) acc[m][n][j] = 0.f;

  // fragment read offsets (swizzled to match stage-source permutation)
  int offA[4], offB[6];
  #pragma unroll
  for (int m = 0; m < 4; ++m) {
    int r = wm * 64 + m * 16 + (lane & 15);
    int sl = (lane >> 4) ^ ((r >> 1) & 3);
    offA[m] = r * 64 + sl * 16;
  }
  #pragma unroll
  for (int n = 0; n < 6; ++n) {
    int r = wn * 96 + n * 16 + (lane & 15);
    int sl = (lane >> 4) ^ ((r >> 1) & 3);
    offB[n] = r * 64 + sl * 16;
  }

  stage(0, 0);
  for (int tk = 0; tk < NTK; ++tk) {
    int cur = tk & 1;
    __syncthreads();               // drains vmcnt(0): staged tile ready
    if (tk + 1 < NTK) stage(tk + 1, cur ^ 1);
    bf16x8 af[4], bfr[6];
    #pragma unroll
    for (int m = 0; m < 4; ++m) af[m] = *(const bf16x8*)(As[cur] + offA[m]);
    #pragma unroll
    for (int n = 0; n < 6; ++n) bfr[n] = *(const bf16x8*)(Bs[cur] + offB[n]);
    #pragma unroll
    for (int m = 0; m < 4; ++m)
      #pragma unroll
      for (int n = 0; n < 6; ++n)
        acc[m][n] = __builtin_amdgcn_mfma_f32_16x16x32_bf16(af[m], bfr[n], acc[m][n], 0, 0, 0);
  }

  // epilogue: sum of squares over this block's 96-col slice, reduce 16 lanes,
  // atomicAdd into norm2[row]  (C/D layout: col=lane&15, row=(lane>>4)*4+reg)
  float ps[4][4];
  #pragma unroll
  for (int m = 0; m < 4; ++m)
    #pragma unroll
    for (int i = 0; i < 4; ++i) {
      float v = 0.f;
      #pragma unroll
      for (int n = 0; n < 6; ++n) { float x = acc[m][n][i]; v += x * x; }
      #pragma unroll
      for (int d = 1; d < 16; d <<= 1) v += __shfl_xor(v, d, 64);
      ps[m][i] = v;
    }
  if ((lane & 15) == 0) {
    int g = lane >> 4;
    #pragma unroll
    for (int m = 0; m < 4; ++m)
      #pragma unroll
      for (int i = 0; i < 4; ++i)
        atomicAdd(&norm2[tm * BM + wm * 64 + m * 16 + g * 4 + i], ps[m][i]);
  }
}

// ---------------- kernel C: cv = relu(sqrt(norm2)*scale); shapley ------------
__global__ __launch_bounds__(128) void kC(const char* __restrict__ ws,
                                          const float* __restrict__ scale,
                                          float* __restrict__ out) {
  const int b = blockIdx.x, n = threadIdx.x;
  const float* norm2 = (const float*)(ws + OFF_N2);
  const float* coefT = (const float*)(ws + OFF_COEF);
  __shared__ float cvs[32];
  if (n < KMC) {
    float nv = norm2[b * KMC + n];
    cvs[n] = fmaxf(sqrtf(fmaxf(nv, 0.f)) * scale[0], 0.f);
  } else if (n < 32) {
    cvs[n] = 0.f;
  }
  __syncthreads();
  float sum = 0.f;
  #pragma unroll
  for (int k = 0; k < KMC; ++k) sum += cvs[k] * coefT[n * 28 + k];
  out[b * NSP + n] = sum;
}

extern "C" void kernel_launch(void* const* d_in, const int* in_sizes, int n_in,
                              void* d_out, int out_size, void* d_ws, size_t ws_size,
                              hipStream_t stream) {
  const float* features   = (const float*)d_in[0];
  const int*   coalitions = (const int*)d_in[1];
  const float* wv         = (const float*)d_in[2];
  const float* scale      = (const float*)d_in[3];
  char* ws = (char*)d_ws;

  prep_kernel<<<202, 256, 0, stream>>>(wv, coalitions, ws);
  dim3 gaa(NB, 4);
  kA<<<gaa, 256, 0, stream>>>(features, (const __hip_bfloat16*)(ws + OFF_CB),
                              (__hip_bfloat16*)(ws + OFF_S));
  kB<<<200, 256, 0, stream>>>(ws);
  kC<<<NB, 128, 0, stream>>>(ws, scale, (float*)d_out);
}

// Round 13
// 46.418 us; speedup vs baseline: 1.6443x; 1.1157x over previous
//
#include <hip/hip_runtime.h>
#include <hip/hip_bf16.h>
#include <stdint.h>

#define NB  256     // batch
#define NSP 128     // n_spins
#define DM  768     // d_model
#define KMC 25      // coalitions
#define MROWS (NB*KMC)  // 6400

// workspace layout (bytes), all 256-aligned (ws is 384 MiB)
#define OFF_S    0u          // s bf16 [6400][768]          9,830,400 B
#define OFF_WT   9830400u    // w_v^T bf16 [768][768]       1,179,648 B
#define OFF_N2   11010048u   // norm2 f32 [6400]               25,600 B
#define OFF_COEF 11035648u   // coefT f32 [128][28]            14,336 B
#define OFF_CB   11049984u   // Cb bf16 [32][128] (pad rows)    8,192 B

typedef __attribute__((ext_vector_type(8))) short bf16x8;
typedef __attribute__((ext_vector_type(4))) float f32x4;
typedef unsigned int u32;

#define GLOAD_LDS16(gp, lp) \
  __builtin_amdgcn_global_load_lds((const __attribute__((address_space(1))) u32*)(gp), \
                                   (__attribute__((address_space(3))) u32*)(lp), 16, 0, 0)

// counted-vmcnt barrier (T4): wait until only the N newest VMEM ops remain.
#define KA_WAITV_BAR(N) asm volatile("s_waitcnt vmcnt(" #N ")\n\ts_barrier" ::: "memory")
// post-read barrier (LDS reads retired) before ring buffers are re-targeted
#define KA_BAR()        asm volatile("s_waitcnt lgkmcnt(0)\n\ts_barrier" ::: "memory")

// ---------------- prep: transpose w_v -> bf16 wT, coef/C tables, zero norm2 -
__global__ __launch_bounds__(256) void prep_kernel(const float* __restrict__ wv,
                                                   const int* __restrict__ co,
                                                   char* __restrict__ ws) {
  const int blk = blockIdx.x;
  const int t = threadIdx.x;
  if (blk < 144) {               // 12x12 tiles of 64x64: wT[n][k] = bf16(wv[k][n])
    __shared__ __hip_bfloat16 lt[64][66];
    const int bi = blk / 12, bj = blk % 12;
    const int k0 = bi * 64, n0 = bj * 64;
    #pragma unroll
    for (int i = 0; i < 16; ++i) {
      int idx = t + i * 256;
      int r = idx >> 6, c = idx & 63;
      lt[c][r] = __float2bfloat16(wv[(size_t)(k0 + r) * DM + n0 + c]);
    }
    __syncthreads();
    __hip_bfloat16* wT = (__hip_bfloat16*)(ws + OFF_WT);
    #pragma unroll
    for (int i = 0; i < 16; ++i) {
      int idx = t + i * 256;
      int r = idx >> 6, c = idx & 63;
      wT[(size_t)(n0 + r) * DM + k0 + c] = lt[r][c];
    }
  } else if (blk == 144) {       // per-(n,k) shapley coefficients
    if (t < NSP) {
      const int n = t;
      int cw = 0;
      #pragma unroll
      for (int k = 0; k < KMC; ++k) cw += co[k * NSP + n];
      const int cwo = KMC - cw;
      const bool valid = (cw > 0) && (cwo > 0);
      float* coefT = (float*)(ws + OFF_COEF);
      #pragma unroll
      for (int k = 0; k < 28; ++k) {
        float v = 0.f;
        if (valid && k < KMC) v = co[k * NSP + n] ? (1.f / (float)cw) : (-1.f / (float)cwo);
        coefT[n * 28 + k] = v;
      }
    }
  } else if (blk < 170) {        // zero norm2 accumulators
    int i = (blk - 145) * 256 + t;
    if (i < MROWS) ((float*)(ws + OFF_N2))[i] = 0.f;
  } else {                       // blk 170..201: Cb row k (bf16, rows>=KMC zero)
    int k = blk - 170;
    if (t < NSP) {
      float v = (k < KMC) ? (float)co[k * NSP + t] : 0.f;
      ((__hip_bfloat16*)(ws + OFF_CB))[k * NSP + t] = __float2bfloat16(v);
    }
  }
}

// ---------------- kernel A: s[b] = C(25x128) x F_b(128x768) via bf16 MFMA ---
// v8 CONTIGUOUS-STREAM: one block per b (grid 256, zero tail) reads its full
// 384 KB f-slab SEQUENTIALLY -- no column slicing, so each DRAM row is
// activated once (r4-r12's 4-way slice split = 4 activations -> ~40% DRAM
// efficiency = the measured 2.4 TB/s wall). 512 thr / 8 waves; 16-row f32
// chunks [16][770-pad] (49,280 B) in a ring-3 (144.4 KB LDS); counted vmcnt;
// ~144 KB/CU outstanding. Pitch 770: fragment reads exactly 2-way bank (free).
// MFMA k-step consumes a chunk PAIR: lane k=hi*8+j -> chunk 2ks+(hi>>1),
// row (hi&1)*8+j (identity hi*8+j=(hi>>1)*16+(hi&1)*8+j keeps A/B aligned).
#define KAP 770   // padded chunk row pitch (floats)

__global__ __launch_bounds__(512, 2) void kA(const float* __restrict__ f,
                                             const __hip_bfloat16* __restrict__ Cb,
                                             __hip_bfloat16* __restrict__ s) {
  const int b = blockIdx.x;
  const int tid = threadIdx.x;
  const int w = tid >> 6;          // 8 waves, 96 d-cols each
  const int lane = tid & 63;
  const int lo = lane & 15, hi = lane >> 4;

  __shared__ __align__(16) float Fs[3][16 * KAP];   // 147,840 B ring

  // A-fragments (coalition rows), k = ks*32 + hi*8 + j (proven mapping)
  bf16x8 A0[4], A1[4];
  #pragma unroll
  for (int ks = 0; ks < 4; ++ks) {
    A0[ks] = *(const bf16x8*)(Cb + (size_t)lo * NSP + ks * 32 + hi * 8);
    A1[ks] = *(const bf16x8*)(Cb + (size_t)(16 + lo) * NSP + ks * 32 + hi * 8);
  }
  asm volatile("s_waitcnt vmcnt(0)" ::: "memory");   // clean vmcnt base

  // DMA geometry: chunk = 16 rows x 768 cols f32 (dense rows, 3 KB each =
  // 3 windows of 1 KB). Wave w stages rows {2w, 2w+1} x 3 segs = 6 windows.
  // LDS dest wave-uniform (row*3080 + seg*1024); HW adds lane*16. Global src
  // per-lane. 16 B segments stay within one dense row (768 = 3*256 exactly).
  int gofs[6], lofs[6];
  #pragma unroll
  for (int q = 0; q < 6; ++q) {
    int rq = q / 3, sg = q - rq * 3;
    int rr = 2 * w + rq;
    gofs[q] = rr * DM + sg * 256 + lane * 4;   // float offset within chunk
    lofs[q] = rr * (KAP * 4) + sg * 1024;      // byte offset within buffer
  }

  const float* fb = f + (size_t)b * NSP * DM;

  f32x4 ac0[6], ac1[6];
  #pragma unroll
  for (int ct = 0; ct < 6; ++ct)
    #pragma unroll
    for (int i = 0; i < 4; ++i) { ac0[ct][i] = 0.f; ac1[ct][i] = 0.f; }

#define KA_ISSUE(ck, bi) { \
    const float* fp_ = fb + (size_t)(ck) * 16 * DM; \
    _Pragma("unroll") for (int q = 0; q < 6; ++q) \
      GLOAD_LDS16(fp_ + gofs[q], (char*)&Fs[(bi)][0] + lofs[q]); }

#define KA_MFMA(ks, blo, bhi) { \
    const float* Fb_ = (hi >> 1) ? &Fs[(bhi)][0] : &Fs[(blo)][0]; \
    const int rb_ = (hi & 1) * 8; \
    _Pragma("unroll") for (int ct = 0; ct < 6; ++ct) { \
      bf16x8 Bf; \
      _Pragma("unroll") for (int j = 0; j < 8; ++j) { \
        float v_ = Fb_[(rb_ + j) * KAP + w * 96 + ct * 16 + lo]; \
        __hip_bfloat16 h_ = __float2bfloat16(v_); \
        Bf[j] = *(short*)&h_; } \
      ac0[ct] = __builtin_amdgcn_mfma_f32_16x16x32_bf16(A0[ks], Bf, ac0[ct], 0, 0, 0); \
      ac1[ct] = __builtin_amdgcn_mfma_f32_16x16x32_bf16(A1[ks], Bf, ac1[ct], 0, 0, 0); } }

  // 8 chunks c0..c7, buffer = ck % 3; ks consumes pair (2ks, 2ks+1)
  KA_ISSUE(0, 0) KA_ISSUE(1, 1) KA_ISSUE(2, 2)   // 18 windows/wave in flight
  KA_WAITV_BAR(6);               // c0,c1 landed (c2 stays in flight)
  KA_MFMA(0, 0, 1)
  KA_BAR();                      // B0,B1 readers retired
  KA_ISSUE(3, 0) KA_ISSUE(4, 1)  // in flight: c2,c3,c4
  KA_WAITV_BAR(6);               // c2,c3 landed (c4 in flight)
  KA_MFMA(1, 2, 0)
  KA_BAR();                      // B2,B0 free
  KA_ISSUE(5, 2) KA_ISSUE(6, 0)  // in flight: c4,c5,c6
  KA_WAITV_BAR(6);               // c4,c5 landed (c6 in flight)
  KA_MFMA(2, 1, 2)
  KA_BAR();                      // B1 free
  KA_ISSUE(7, 1)                 // in flight: c6,c7
  KA_WAITV_BAR(0);               // all landed (epilogue drain fine)
  KA_MFMA(3, 0, 1)

#undef KA_ISSUE
#undef KA_MFMA

  // epilogue: D layout col=lane&15, row=(lane>>4)*4+i
  #pragma unroll
  for (int ct = 0; ct < 6; ++ct) {
    int dcol = w * 96 + ct * 16 + lo;
    #pragma unroll
    for (int i = 0; i < 4; ++i) {
      int r0 = hi * 4 + i;
      s[((size_t)b * KMC + r0) * DM + dcol] = __float2bfloat16(ac0[ct][i]);
      int r1 = 16 + hi * 4 + i;
      if (r1 < KMC)
        s[((size_t)b * KMC + r1) * DM + dcol] = __float2bfloat16(ac1[ct][i]);
    }
  }
}

// ---------------- kernel B: norm2[row] += rowwise |s @ wT^T|^2 (bf16 MFMA) ---
// v2: BM 128->64, grid 200->400 so every CU gets work and ~2 blocks/CU
// co-reside -- implicit block-level overlap (m114) hides the per-K-step
// __syncthreads vmcnt drains that made v1 a ~14us serial chain on 200 CUs.
#define BM 64
#define BN 192
#define BK 32
#define NTK 24   // 768/32

__global__ __launch_bounds__(256) void kB(char* __restrict__ ws) {
  const int bid = blockIdx.x;      // grid 400 = 100 (M) * 4 (N)
  const int tm = bid >> 2;
  const int tn = bid & 3;
  const int tid = threadIdx.x;
  const int wid = tid >> 6;
  const int lane = tid & 63;
  const int wm = wid >> 1;         // 2x2 wave grid: 32 rows x 96 cols per wave
  const int wn = wid & 1;

  const __hip_bfloat16* S  = (const __hip_bfloat16*)(ws + OFF_S);
  const __hip_bfloat16* WT = (const __hip_bfloat16*)(ws + OFF_WT);
  float* norm2 = (float*)(ws + OFF_N2);

  __shared__ __align__(16) char As[2][BM * BK * 2];  // [64][32] bf16, 64B rows
  __shared__ __align__(16) char Bs[2][BN * BK * 2];  // [192][32] bf16, 64B rows

  // staging: global src pre-swizzled (slot ^= (r>>1)&3), LDS dest linear
  // A: 4 windows total -> 1 per wave
  const char* gA; char *lAA0, *lAA1;
  {
    int li = wid * 64 + lane;
    int r = li >> 2, sl = li & 3;
    int slx = sl ^ ((r >> 1) & 3);
    gA = (const char*)(S + (size_t)(tm * BM + r) * DM) + slx * 16;
    lAA0 = As[0] + wid * 1024;
    lAA1 = As[1] + wid * 1024;
  }
  const char* gB[3]; char *lB0[3], *lB1[3];
  #pragma unroll
  for (int j = 0; j < 3; ++j) {
    int li = (wid * 3 + j) * 64 + lane;
    int r = li >> 2, sl = li & 3;
    int slx = sl ^ ((r >> 1) & 3);
    gB[j] = (const char*)(WT + (size_t)(tn * BN + r) * DM) + slx * 16;
    lB0[j] = Bs[0] + (wid * 3 + j) * 1024;
    lB1[j] = Bs[1] + (wid * 3 + j) * 1024;
  }

  auto stage = [&](int tk, int bsel) {
    size_t koff = (size_t)tk * (BK * 2);   // 64 bytes per K-step
    GLOAD_LDS16(gA + koff, bsel ? lAA1 : lAA0);
    #pragma unroll
    for (int j = 0; j < 3; ++j) GLOAD_LDS16(gB[j] + koff, bsel ? lB1[j] : lB0[j]);
  };

  f32x4 acc[2][6];
  #pragma unroll
  for (int m = 0; m < 2; ++m)
    #pragma unroll
    for (int n = 0; n < 6; ++n)
      #pragma unroll
      for (int j = 0; j < 4; ++j) acc[m][n][j] = 0.f;

  // fragment read offsets (swizzled to match stage-source permutation)
  int offA[2], offB[6];
  #pragma unroll
  for (int m = 0; m < 2; ++m) {
    int r = wm * 32 + m * 16 + (lane & 15);
    int sl = (lane >> 4) ^ ((r >> 1) & 3);
    offA[m] = r * 64 + sl * 16;
  }
  #pragma unroll
  for (int n = 0; n < 6; ++n) {
    int r = wn * 96 + n * 16 + (lane & 15);
    int sl = (lane >> 4) ^ ((r >> 1) & 3);
    offB[n] = r * 64 + sl * 16;
  }

  stage(0, 0);
  for (int tk = 0; tk < NTK; ++tk) {
    int cur = tk & 1;
    __syncthreads();               // drains vmcnt(0): staged tile ready
    if (tk + 1 < NTK) stage(tk + 1, cur ^ 1);
    bf16x8 af[2], bfr[6];
    #pragma unroll
    for (int m = 0; m < 2; ++m) af[m] = *(const bf16x8*)(As[cur] + offA[m]);
    #pragma unroll
    for (int n = 0; n < 6; ++n) bfr[n] = *(const bf16x8*)(Bs[cur] + offB[n]);
    #pragma unroll
    for (int m = 0; m < 2; ++m)
      #pragma unroll
      for (int n = 0; n < 6; ++n)
        acc[m][n] = __builtin_amdgcn_mfma_f32_16x16x32_bf16(af[m], bfr[n], acc[m][n], 0, 0, 0);
  }

  // epilogue: sum of squares over this block's 96-col slice, reduce 16 lanes,
  // atomicAdd into norm2[row]  (C/D layout: col=lane&15, row=(lane>>4)*4+reg)
  float ps[2][4];
  #pragma unroll
  for (int m = 0; m < 2; ++m)
    #pragma unroll
    for (int i = 0; i < 4; ++i) {
      float v = 0.f;
      #pragma unroll
      for (int n = 0; n < 6; ++n) { float x = acc[m][n][i]; v += x * x; }
      #pragma unroll
      for (int d = 1; d < 16; d <<= 1) v += __shfl_xor(v, d, 64);
      ps[m][i] = v;
    }
  if ((lane & 15) == 0) {
    int g = lane >> 4;
    #pragma unroll
    for (int m = 0; m < 2; ++m)
      #pragma unroll
      for (int i = 0; i < 4; ++i)
        atomicAdd(&norm2[tm * BM + wm * 32 + m * 16 + g * 4 + i], ps[m][i]);
  }
}

// ---------------- kernel C: cv = relu(sqrt(norm2)*scale); shapley ------------
__global__ __launch_bounds__(128) void kC(const char* __restrict__ ws,
                                          const float* __restrict__ scale,
                                          float* __restrict__ out) {
  const int b = blockIdx.x, n = threadIdx.x;
  const float* norm2 = (const float*)(ws + OFF_N2);
  const float* coefT = (const float*)(ws + OFF_COEF);
  __shared__ float cvs[32];
  if (n < KMC) {
    float nv = norm2[b * KMC + n];
    cvs[n] = fmaxf(sqrtf(fmaxf(nv, 0.f)) * scale[0], 0.f);
  } else if (n < 32) {
    cvs[n] = 0.f;
  }
  __syncthreads();
  float sum = 0.f;
  #pragma unroll
  for (int k = 0; k < KMC; ++k) sum += cvs[k] * coefT[n * 28 + k];
  out[b * NSP + n] = sum;
}

extern "C" void kernel_launch(void* const* d_in, const int* in_sizes, int n_in,
                              void* d_out, int out_size, void* d_ws, size_t ws_size,
                              hipStream_t stream) {
  const float* features   = (const float*)d_in[0];
  const int*   coalitions = (const int*)d_in[1];
  const float* wv         = (const float*)d_in[2];
  const float* scale      = (const float*)d_in[3];
  char* ws = (char*)d_ws;

  prep_kernel<<<202, 256, 0, stream>>>(wv, coalitions, ws);
  kA<<<NB, 512, 0, stream>>>(features, (const __hip_bfloat16*)(ws + OFF_CB),
                             (__hip_bfloat16*)(ws + OFF_S));
  kB<<<400, 256, 0, stream>>>(ws);
  kC<<<NB, 128, 0, stream>>>(ws, scale, (float*)d_out);
}

// Round 14
// 45.989 us; speedup vs baseline: 1.6596x; 1.0093x over previous
//
#include <hip/hip_runtime.h>
#include <hip/hip_bf16.h>
#include <stdint.h>

#define NB  256     // batch
#define NSP 128     // n_spins
#define DM  768     // d_model
#define KMC 25      // coalitions
#define MROWS (NB*KMC)  // 6400

// workspace layout (bytes), all 256-aligned (ws is 384 MiB)
#define OFF_S    0u          // s bf16 [6400][768]          9,830,400 B
#define OFF_WT   9830400u    // w_v^T bf16 [768][768]       1,179,648 B
#define OFF_N2   11010048u   // norm2 f32 [6400]               25,600 B
#define OFF_COEF 11035648u   // coefT f32 [128][28]            14,336 B
#define OFF_CB   11049984u   // Cb bf16 [32][128] (pad rows)    8,192 B

typedef __attribute__((ext_vector_type(8))) short bf16x8;
typedef __attribute__((ext_vector_type(4))) float f32x4;
typedef __attribute__((ext_vector_type(16))) float f32x16;
typedef unsigned int u32;

#define GLOAD_LDS16(gp, lp) \
  __builtin_amdgcn_global_load_lds((const __attribute__((address_space(1))) u32*)(gp), \
                                   (__attribute__((address_space(3))) u32*)(lp), 16, 0, 0)

// counted-vmcnt barrier (T4): wait until only the N newest VMEM ops remain
// (per-wave), then s_barrier (so ALL waves' windows for the chunk are landed).
#define KA_WAITV_BAR(N) asm volatile("s_waitcnt vmcnt(" #N ")\n\ts_barrier" ::: "memory")
// read-retirement barrier before a ring buffer is re-targeted by DMA
#define KA_BAR()        asm volatile("s_barrier" ::: "memory")

// ---------------- prep: transpose w_v -> bf16 wT, coef/C tables, zero norm2 -
__global__ __launch_bounds__(256) void prep_kernel(const float* __restrict__ wv,
                                                   const int* __restrict__ co,
                                                   char* __restrict__ ws) {
  const int blk = blockIdx.x;
  const int t = threadIdx.x;
  if (blk < 144) {               // 12x12 tiles of 64x64: wT[n][k] = bf16(wv[k][n])
    __shared__ __hip_bfloat16 lt[64][66];
    const int bi = blk / 12, bj = blk % 12;
    const int k0 = bi * 64, n0 = bj * 64;
    #pragma unroll
    for (int i = 0; i < 16; ++i) {
      int idx = t + i * 256;
      int r = idx >> 6, c = idx & 63;
      lt[c][r] = __float2bfloat16(wv[(size_t)(k0 + r) * DM + n0 + c]);
    }
    __syncthreads();
    __hip_bfloat16* wT = (__hip_bfloat16*)(ws + OFF_WT);
    #pragma unroll
    for (int i = 0; i < 16; ++i) {
      int idx = t + i * 256;
      int r = idx >> 6, c = idx & 63;
      wT[(size_t)(n0 + r) * DM + k0 + c] = lt[r][c];
    }
  } else if (blk == 144) {       // per-(n,k) shapley coefficients
    if (t < NSP) {
      const int n = t;
      int cw = 0;
      #pragma unroll
      for (int k = 0; k < KMC; ++k) cw += co[k * NSP + n];
      const int cwo = KMC - cw;
      const bool valid = (cw > 0) && (cwo > 0);
      float* coefT = (float*)(ws + OFF_COEF);
      #pragma unroll
      for (int k = 0; k < 28; ++k) {
        float v = 0.f;
        if (valid && k < KMC) v = co[k * NSP + n] ? (1.f / (float)cw) : (-1.f / (float)cwo);
        coefT[n * 28 + k] = v;
      }
    }
  } else if (blk < 170) {        // zero norm2 accumulators
    int i = (blk - 145) * 256 + t;
    if (i < MROWS) ((float*)(ws + OFF_N2))[i] = 0.f;
  } else {                       // blk 170..201: Cb row k (bf16, rows>=KMC zero)
    int k = blk - 170;
    if (t < NSP) {
      float v = (k < KMC) ? (float)co[k * NSP + t] : 0.f;
      ((__hip_bfloat16*)(ws + OFF_CB))[k * NSP + t] = __float2bfloat16(v);
    }
  }
}

// ---------------- kernel A: s[b] = C(25x128) x F_b(128x768) via bf16 MFMA ---
// v9: one chunk == one K-step. 32x32x16 MFMA (K=16) so each full-width
// 16-row f32 chunk [16][768] (48 KB) is consumed by exactly ONE K-step --
// the ring-3 schedule then waits on chunks issued THREE steps earlier
// (r4-r13's pair-consumption waited on chunks issued zero steps earlier ->
// full latency exposed every step -> the measured 2.5-4 TB/s wall).
// Grid 256 (1 block/b, contiguous 384 KB stream), 512 thr / 8 waves,
// 144 KB LDS ring. M=32 covers all 25 rows in ONE A-fragment; 3 N-tiles
// (32 cols) per wave; acc = 3 x f32x16. B-frag ds_reads are 2-way-bank (free):
// lanes 0-31 read 32 consecutive f32. D layout (m74/m101-verified):
// col=lane&31, row=(reg&3)+8*(reg>>2)+4*(lane>>5).
#define KACH (16 * 768)   // floats per chunk

__global__ __launch_bounds__(512, 2) void kA(const float* __restrict__ f,
                                             const __hip_bfloat16* __restrict__ Cb,
                                             __hip_bfloat16* __restrict__ s) {
  const int b = blockIdx.x;
  const int tid = threadIdx.x;
  const int w = tid >> 6;          // 8 waves, 96 d-cols each
  const int lane = tid & 63;
  const int l31 = lane & 31, l5 = lane >> 5;

  __shared__ __align__(16) float Fs[3][KACH];   // 147,456 B ring

  // A-fragments for all 8 K-steps: row = lane&31, k = ks*16 + l5*8 + j
  bf16x8 Af[8];
  #pragma unroll
  for (int ks = 0; ks < 8; ++ks)
    Af[ks] = *(const bf16x8*)(Cb + (size_t)l31 * NSP + ks * 16 + l5 * 8);
  asm volatile("s_waitcnt vmcnt(0)" ::: "memory");   // clean vmcnt base

  // staging: 48 windows of 1 KB per chunk, 6 per wave; window i covers
  // floats [i*256, i*256+256) of the chunk (chunk rows are contiguous in f,
  // so global float offset == LDS float offset). Per-lane global src
  // (lane*4 floats = 16 B, coalesced); LDS dest linear (wave-uniform + lane*16).
  const float* fb = f + (size_t)b * NSP * DM;

  f32x16 ac[3];
  #pragma unroll
  for (int nt = 0; nt < 3; ++nt)
    #pragma unroll
    for (int r = 0; r < 16; ++r) ac[nt][r] = 0.f;

#define KA_ISSUE(ck, bi) { \
    const float* fp_ = fb + (size_t)(ck) * KACH; \
    _Pragma("unroll") for (int q = 0; q < 6; ++q) \
      GLOAD_LDS16(fp_ + (w * 6 + q) * 256 + lane * 4, \
                  (char*)&Fs[(bi)][0] + ((w * 6 + q) << 10)); }

#define KA_MFMA(ks, bi) { \
    _Pragma("unroll") for (int nt = 0; nt < 3; ++nt) { \
      bf16x8 Bf; \
      _Pragma("unroll") for (int j = 0; j < 8; ++j) { \
        float v_ = Fs[(bi)][(l5 * 8 + j) * 768 + w * 96 + nt * 32 + l31]; \
        __hip_bfloat16 h_ = __float2bfloat16(v_); \
        Bf[j] = *(short*)&h_; } \
      ac[nt] = __builtin_amdgcn_mfma_f32_32x32x16_bf16(Af[ks], Bf, ac[nt], 0, 0, 0); } }

  // ring-3 schedule: wait target always issued >=3 steps prior (steady state)
  KA_ISSUE(0, 0) KA_ISSUE(1, 1) KA_ISSUE(2, 2)   // 18 windows/wave in flight
  KA_WAITV_BAR(12);  KA_MFMA(0, 0)  KA_BAR();  KA_ISSUE(3, 0)
  KA_WAITV_BAR(12);  KA_MFMA(1, 1)  KA_BAR();  KA_ISSUE(4, 1)
  KA_WAITV_BAR(12);  KA_MFMA(2, 2)  KA_BAR();  KA_ISSUE(5, 2)
  KA_WAITV_BAR(12);  KA_MFMA(3, 0)  KA_BAR();  KA_ISSUE(6, 0)
  KA_WAITV_BAR(12);  KA_MFMA(4, 1)  KA_BAR();  KA_ISSUE(7, 1)
  KA_WAITV_BAR(12);  KA_MFMA(5, 2)
  KA_WAITV_BAR(6);   KA_MFMA(6, 0)
  KA_WAITV_BAR(0);   KA_MFMA(7, 1)

#undef KA_ISSUE
#undef KA_MFMA

  // epilogue: D col = lane&31, row = (r&3) + 8*(r>>2) + 4*l5; rows >=25 dropped
  #pragma unroll
  for (int nt = 0; nt < 3; ++nt) {
    int dcol = w * 96 + nt * 32 + l31;
    #pragma unroll
    for (int r = 0; r < 16; ++r) {
      int row = (r & 3) + 8 * (r >> 2) + 4 * l5;
      if (row < KMC)
        s[((size_t)b * KMC + row) * DM + dcol] = __float2bfloat16(ac[nt][r]);
    }
  }
}

// ---------------- kernel B: norm2[row] += rowwise |s @ wT^T|^2 (bf16 MFMA) ---
#define BM 64
#define BN 192
#define BK 32
#define NTK 24   // 768/32

__global__ __launch_bounds__(256) void kB(char* __restrict__ ws) {
  const int bid = blockIdx.x;      // grid 400 = 100 (M) * 4 (N)
  const int tm = bid >> 2;
  const int tn = bid & 3;
  const int tid = threadIdx.x;
  const int wid = tid >> 6;
  const int lane = tid & 63;
  const int wm = wid >> 1;         // 2x2 wave grid: 32 rows x 96 cols per wave
  const int wn = wid & 1;

  const __hip_bfloat16* S  = (const __hip_bfloat16*)(ws + OFF_S);
  const __hip_bfloat16* WT = (const __hip_bfloat16*)(ws + OFF_WT);
  float* norm2 = (float*)(ws + OFF_N2);

  __shared__ __align__(16) char As[2][BM * BK * 2];  // [64][32] bf16, 64B rows
  __shared__ __align__(16) char Bs[2][BN * BK * 2];  // [192][32] bf16, 64B rows

  // staging: global src pre-swizzled (slot ^= (r>>1)&3), LDS dest linear
  const char* gA; char *lAA0, *lAA1;
  {
    int li = wid * 64 + lane;
    int r = li >> 2, sl = li & 3;
    int slx = sl ^ ((r >> 1) & 3);
    gA = (const char*)(S + (size_t)(tm * BM + r) * DM) + slx * 16;
    lAA0 = As[0] + wid * 1024;
    lAA1 = As[1] + wid * 1024;
  }
  const char* gB[3]; char *lB0[3], *lB1[3];
  #pragma unroll
  for (int j = 0; j < 3; ++j) {
    int li = (wid * 3 + j) * 64 + lane;
    int r = li >> 2, sl = li & 3;
    int slx = sl ^ ((r >> 1) & 3);
    gB[j] = (const char*)(WT + (size_t)(tn * BN + r) * DM) + slx * 16;
    lB0[j] = Bs[0] + (wid * 3 + j) * 1024;
    lB1[j] = Bs[1] + (wid * 3 + j) * 1024;
  }

  auto stage = [&](int tk, int bsel) {
    size_t koff = (size_t)tk * (BK * 2);   // 64 bytes per K-step
    GLOAD_LDS16(gA + koff, bsel ? lAA1 : lAA0);
    #pragma unroll
    for (int j = 0; j < 3; ++j) GLOAD_LDS16(gB[j] + koff, bsel ? lB1[j] : lB0[j]);
  };

  f32x4 acc[2][6];
  #pragma unroll
  for (int m = 0; m < 2; ++m)
    #pragma unroll
    for (int n = 0; n < 6; ++n)
      #pragma unroll
      for (int j = 0; j < 4; ++j) acc[m][n][j] = 0.f;

  // fragment read offsets (swizzled to match stage-source permutation)
  int offA[2], offB[6];
  #pragma unroll
  for (int m = 0; m < 2; ++m) {
    int r = wm * 32 + m * 16 + (lane & 15);
    int sl = (lane >> 4) ^ ((r >> 1) & 3);
    offA[m] = r * 64 + sl * 16;
  }
  #pragma unroll
  for (int n = 0; n < 6; ++n) {
    int r = wn * 96 + n * 16 + (lane & 15);
    int sl = (lane >> 4) ^ ((r >> 1) & 3);
    offB[n] = r * 64 + sl * 16;
  }

  stage(0, 0);
  for (int tk = 0; tk < NTK; ++tk) {
    int cur = tk & 1;
    __syncthreads();               // drains vmcnt(0): staged tile ready
    if (tk + 1 < NTK) stage(tk + 1, cur ^ 1);
    bf16x8 af[2], bfr[6];
    #pragma unroll
    for (int m = 0; m < 2; ++m) af[m] = *(const bf16x8*)(As[cur] + offA[m]);
    #pragma unroll
    for (int n = 0; n < 6; ++n) bfr[n] = *(const bf16x8*)(Bs[cur] + offB[n]);
    #pragma unroll
    for (int m = 0; m < 2; ++m)
      #pragma unroll
      for (int n = 0; n < 6; ++n)
        acc[m][n] = __builtin_amdgcn_mfma_f32_16x16x32_bf16(af[m], bfr[n], acc[m][n], 0, 0, 0);
  }

  // epilogue: sum of squares over this block's 96-col slice, reduce 16 lanes,
  // atomicAdd into norm2[row]  (C/D layout: col=lane&15, row=(lane>>4)*4+reg)
  float ps[2][4];
  #pragma unroll
  for (int m = 0; m < 2; ++m)
    #pragma unroll
    for (int i = 0; i < 4; ++i) {
      float v = 0.f;
      #pragma unroll
      for (int n = 0; n < 6; ++n) { float x = acc[m][n][i]; v += x * x; }
      #pragma unroll
      for (int d = 1; d < 16; d <<= 1) v += __shfl_xor(v, d, 64);
      ps[m][i] = v;
    }
  if ((lane & 15) == 0) {
    int g = lane >> 4;
    #pragma unroll
    for (int m = 0; m < 2; ++m)
      #pragma unroll
      for (int i = 0; i < 4; ++i)
        atomicAdd(&norm2[tm * BM + wm * 32 + m * 16 + g * 4 + i], ps[m][i]);
  }
}

// ---------------- kernel C: cv = relu(sqrt(norm2)*scale); shapley ------------
__global__ __launch_bounds__(128) void kC(const char* __restrict__ ws,
                                          const float* __restrict__ scale,
                                          float* __restrict__ out) {
  const int b = blockIdx.x, n = threadIdx.x;
  const float* norm2 = (const float*)(ws + OFF_N2);
  const float* coefT = (const float*)(ws + OFF_COEF);
  __shared__ float cvs[32];
  if (n < KMC) {
    float nv = norm2[b * KMC + n];
    cvs[n] = fmaxf(sqrtf(fmaxf(nv, 0.f)) * scale[0], 0.f);
  } else if (n < 32) {
    cvs[n] = 0.f;
  }
  __syncthreads();
  float sum = 0.f;
  #pragma unroll
  for (int k = 0; k < KMC; ++k) sum += cvs[k] * coefT[n * 28 + k];
  out[b * NSP + n] = sum;
}

extern "C" void kernel_launch(void* const* d_in, const int* in_sizes, int n_in,
                              void* d_out, int out_size, void* d_ws, size_t ws_size,
                              hipStream_t stream) {
  const float* features   = (const float*)d_in[0];
  const int*   coalitions = (const int*)d_in[1];
  const float* wv         = (const float*)d_in[2];
  const float* scale      = (const float*)d_in[3];
  char* ws = (char*)d_ws;

  prep_kernel<<<202, 256, 0, stream>>>(wv, coalitions, ws);
  kA<<<NB, 512, 0, stream>>>(features, (const __hip_bfloat16*)(ws + OFF_CB),
                             (__hip_bfloat16*)(ws + OFF_S));
  kB<<<400, 256, 0, stream>>>(ws);
  kC<<<NB, 128, 0, stream>>>(ws, scale, (float*)d_out);
}

// Round 15
// 45.867 us; speedup vs baseline: 1.6640x; 1.0027x over previous
//
#include <hip/hip_runtime.h>
#include <hip/hip_bf16.h>
#include <stdint.h>

#define NB  256     // batch
#define NSP 128     // n_spins
#define DM  768     // d_model
#define KMC 25      // coalitions
#define MROWS (NB*KMC)  // 6400

// workspace layout (bytes), all 256-aligned (ws is 384 MiB)
#define OFF_S    0u          // s bf16 [6400][768]          9,830,400 B
#define OFF_WT   9830400u    // w_v^T bf16 [768][768]       1,179,648 B
#define OFF_N2   11010048u   // norm2 f32 [6400]               25,600 B
#define OFF_COEF 11035648u   // coefT f32 [128][28]            14,336 B
#define OFF_CB   11049984u   // Cb bf16 [32][128] (pad rows)    8,192 B

typedef __attribute__((ext_vector_type(8))) short bf16x8;
typedef __attribute__((ext_vector_type(4))) float f32x4;
typedef __attribute__((ext_vector_type(16))) float f32x16;
typedef unsigned int u32;

#define GLOAD_LDS16(gp, lp) \
  __builtin_amdgcn_global_load_lds((const __attribute__((address_space(1))) u32*)(gp), \
                                   (__attribute__((address_space(3))) u32*)(lp), 16, 0, 0)

// counted-vmcnt barrier (T4): wait until only the N newest VMEM ops remain
// (per-wave), then s_barrier (so ALL waves' windows for the chunk are landed).
#define KA_WAITV_BAR(N) asm volatile("s_waitcnt vmcnt(" #N ")\n\ts_barrier" ::: "memory")
// read-retirement barrier before a ring buffer is re-targeted by DMA
#define KA_BAR()        asm volatile("s_barrier" ::: "memory")

// ---------------- prep: transpose w_v -> bf16 wT, coef/C tables, zero norm2 -
__global__ __launch_bounds__(256) void prep_kernel(const float* __restrict__ wv,
                                                   const int* __restrict__ co,
                                                   char* __restrict__ ws) {
  const int blk = blockIdx.x;
  const int t = threadIdx.x;
  if (blk < 144) {               // 12x12 tiles of 64x64: wT[n][k] = bf16(wv[k][n])
    __shared__ __hip_bfloat16 lt[64][66];
    const int bi = blk / 12, bj = blk % 12;
    const int k0 = bi * 64, n0 = bj * 64;
    #pragma unroll
    for (int i = 0; i < 16; ++i) {
      int idx = t + i * 256;
      int r = idx >> 6, c = idx & 63;
      lt[c][r] = __float2bfloat16(wv[(size_t)(k0 + r) * DM + n0 + c]);
    }
    __syncthreads();
    __hip_bfloat16* wT = (__hip_bfloat16*)(ws + OFF_WT);
    #pragma unroll
    for (int i = 0; i < 16; ++i) {
      int idx = t + i * 256;
      int r = idx >> 6, c = idx & 63;
      wT[(size_t)(n0 + r) * DM + k0 + c] = lt[r][c];
    }
  } else if (blk == 144) {       // per-(n,k) shapley coefficients
    if (t < NSP) {
      const int n = t;
      int cw = 0;
      #pragma unroll
      for (int k = 0; k < KMC; ++k) cw += co[k * NSP + n];
      const int cwo = KMC - cw;
      const bool valid = (cw > 0) && (cwo > 0);
      float* coefT = (float*)(ws + OFF_COEF);
      #pragma unroll
      for (int k = 0; k < 28; ++k) {
        float v = 0.f;
        if (valid && k < KMC) v = co[k * NSP + n] ? (1.f / (float)cw) : (-1.f / (float)cwo);
        coefT[n * 28 + k] = v;
      }
    }
  } else if (blk < 170) {        // zero norm2 accumulators
    int i = (blk - 145) * 256 + t;
    if (i < MROWS) ((float*)(ws + OFF_N2))[i] = 0.f;
  } else {                       // blk 170..201: Cb row k (bf16, rows>=KMC zero)
    int k = blk - 170;
    if (t < NSP) {
      float v = (k < KMC) ? (float)co[k * NSP + t] : 0.f;
      ((__hip_bfloat16*)(ws + OFF_CB))[k * NSP + t] = __float2bfloat16(v);
    }
  }
}

// ---------------- kernel A: s[b] = C(25x128) x F_b(128x768) via bf16 MFMA ---
// v10: v9's ring-3 one-chunk-one-K-step schedule, but TWO independent blocks
// per CU so barrier/prologue dead-time of one block is covered by the sibling
// (m114 overlap). Grid (256 b x 2 d-halves) = 512 blocks, 256 thr / 4 waves,
// chunk = [16 rows][384 cols] f32 (24 KB), ring-3 = 72 KB LDS -> 2 blocks/CU,
// all 256 CUs busy. Per-CU arithmetic: steady-state = BW-paced (10.25 B/cyc
// share), jitter hidden. Fragment maps identical to v9 (m74/m101-verified
// 32x32 D layout). vmcnt counts unchanged (6 windows/wave/chunk).
#define KACH (16 * 384)   // floats per chunk

__global__ __launch_bounds__(256, 2) void kA(const float* __restrict__ f,
                                             const __hip_bfloat16* __restrict__ Cb,
                                             __hip_bfloat16* __restrict__ s) {
  const int b = blockIdx.x;
  const int half = blockIdx.y;     // d-half: cols [half*384, half*384+384)
  const int tid = threadIdx.x;
  const int w = tid >> 6;          // 4 waves, 96 d-cols each
  const int lane = tid & 63;
  const int l31 = lane & 31, l5 = lane >> 5;

  __shared__ __align__(16) float Fs[3][KACH];   // 73,728 B ring

  // A-fragments for all 8 K-steps: row = lane&31, k = ks*16 + l5*8 + j
  bf16x8 Af[8];
  #pragma unroll
  for (int ks = 0; ks < 8; ++ks)
    Af[ks] = *(const bf16x8*)(Cb + (size_t)l31 * NSP + ks * 16 + l5 * 8);
  asm volatile("s_waitcnt vmcnt(0)" ::: "memory");   // clean vmcnt base

  // staging: chunk = [16][384] f32 = 24 windows of 1 KB, 6 per wave.
  // Window wi covers floats [wi*256, wi*256+256); lane 16B segments never
  // cross a 384-col row boundary (all crossings 4-float aligned).
  const float* fb = f + (size_t)b * NSP * DM + half * 384;
  int goff[6];
  #pragma unroll
  for (int q = 0; q < 6; ++q) {
    int e = (w * 6 + q) * 256 + lane * 4;
    int r = e / 384, c = e - r * 384;
    goff[q] = r * DM + c;
  }

  f32x16 ac[3];
  #pragma unroll
  for (int nt = 0; nt < 3; ++nt)
    #pragma unroll
    for (int r = 0; r < 16; ++r) ac[nt][r] = 0.f;

#define KA_ISSUE(ck, bi) { \
    const float* fp_ = fb + (size_t)(ck) * 16 * DM; \
    _Pragma("unroll") for (int q = 0; q < 6; ++q) \
      GLOAD_LDS16(fp_ + goff[q], (char*)&Fs[(bi)][0] + ((w * 6 + q) << 10)); }

#define KA_MFMA(ks, bi) { \
    _Pragma("unroll") for (int nt = 0; nt < 3; ++nt) { \
      bf16x8 Bf; \
      _Pragma("unroll") for (int j = 0; j < 8; ++j) { \
        float v_ = Fs[(bi)][(l5 * 8 + j) * 384 + w * 96 + nt * 32 + l31]; \
        __hip_bfloat16 h_ = __float2bfloat16(v_); \
        Bf[j] = *(short*)&h_; } \
      ac[nt] = __builtin_amdgcn_mfma_f32_32x32x16_bf16(Af[ks], Bf, ac[nt], 0, 0, 0); } }

  // ring-3 schedule: wait target always issued >=3 steps prior (steady state)
  KA_ISSUE(0, 0) KA_ISSUE(1, 1) KA_ISSUE(2, 2)   // 18 windows/wave in flight
  KA_WAITV_BAR(12);  KA_MFMA(0, 0)  KA_BAR();  KA_ISSUE(3, 0)
  KA_WAITV_BAR(12);  KA_MFMA(1, 1)  KA_BAR();  KA_ISSUE(4, 1)
  KA_WAITV_BAR(12);  KA_MFMA(2, 2)  KA_BAR();  KA_ISSUE(5, 2)
  KA_WAITV_BAR(12);  KA_MFMA(3, 0)  KA_BAR();  KA_ISSUE(6, 0)
  KA_WAITV_BAR(12);  KA_MFMA(4, 1)  KA_BAR();  KA_ISSUE(7, 1)
  KA_WAITV_BAR(12);  KA_MFMA(5, 2)
  KA_WAITV_BAR(6);   KA_MFMA(6, 0)
  KA_WAITV_BAR(0);   KA_MFMA(7, 1)

#undef KA_ISSUE
#undef KA_MFMA

  // epilogue: D col = lane&31, row = (r&3) + 8*(r>>2) + 4*l5; rows >=25 dropped
  #pragma unroll
  for (int nt = 0; nt < 3; ++nt) {
    int dcol = half * 384 + w * 96 + nt * 32 + l31;
    #pragma unroll
    for (int r = 0; r < 16; ++r) {
      int row = (r & 3) + 8 * (r >> 2) + 4 * l5;
      if (row < KMC)
        s[((size_t)b * KMC + row) * DM + dcol] = __float2bfloat16(ac[nt][r]);
    }
  }
}

// ---------------- kernel B: norm2[row] += rowwise |s @ wT^T|^2 (bf16 MFMA) ---
#define BM 64
#define BN 192
#define BK 32
#define NTK 24   // 768/32

__global__ __launch_bounds__(256) void kB(char* __restrict__ ws) {
  const int bid = blockIdx.x;      // grid 400 = 100 (M) * 4 (N)
  const int tm = bid >> 2;
  const int tn = bid & 3;
  const int tid = threadIdx.x;
  const int wid = tid >> 6;
  const int lane = tid & 63;
  const int wm = wid >> 1;         // 2x2 wave grid: 32 rows x 96 cols per wave
  const int wn = wid & 1;

  const __hip_bfloat16* S  = (const __hip_bfloat16*)(ws + OFF_S);
  const __hip_bfloat16* WT = (const __hip_bfloat16*)(ws + OFF_WT);
  float* norm2 = (float*)(ws + OFF_N2);

  __shared__ __align__(16) char As[2][BM * BK * 2];  // [64][32] bf16, 64B rows
  __shared__ __align__(16) char Bs[2][BN * BK * 2];  // [192][32] bf16, 64B rows

  // staging: global src pre-swizzled (slot ^= (r>>1)&3), LDS dest linear
  const char* gA; char *lAA0, *lAA1;
  {
    int li = wid * 64 + lane;
    int r = li >> 2, sl = li & 3;
    int slx = sl ^ ((r >> 1) & 3);
    gA = (const char*)(S + (size_t)(tm * BM + r) * DM) + slx * 16;
    lAA0 = As[0] + wid * 1024;
    lAA1 = As[1] + wid * 1024;
  }
  const char* gB[3]; char *lB0[3], *lB1[3];
  #pragma unroll
  for (int j = 0; j < 3; ++j) {
    int li = (wid * 3 + j) * 64 + lane;
    int r = li >> 2, sl = li & 3;
    int slx = sl ^ ((r >> 1) & 3);
    gB[j] = (const char*)(WT + (size_t)(tn * BN + r) * DM) + slx * 16;
    lB0[j] = Bs[0] + (wid * 3 + j) * 1024;
    lB1[j] = Bs[1] + (wid * 3 + j) * 1024;
  }

  auto stage = [&](int tk, int bsel) {
    size_t koff = (size_t)tk * (BK * 2);   // 64 bytes per K-step
    GLOAD_LDS16(gA + koff, bsel ? lAA1 : lAA0);
    #pragma unroll
    for (int j = 0; j < 3; ++j) GLOAD_LDS16(gB[j] + koff, bsel ? lB1[j] : lB0[j]);
  };

  f32x4 acc[2][6];
  #pragma unroll
  for (int m = 0; m < 2; ++m)
    #pragma unroll
    for (int n = 0; n < 6; ++n)
      #pragma unroll
      for (int j = 0; j < 4; ++j) acc[m][n][j] = 0.f;

  // fragment read offsets (swizzled to match stage-source permutation)
  int offA[2], offB[6];
  #pragma unroll
  for (int m = 0; m < 2; ++m) {
    int r = wm * 32 + m * 16 + (lane & 15);
    int sl = (lane >> 4) ^ ((r >> 1) & 3);
    offA[m] = r * 64 + sl * 16;
  }
  #pragma unroll
  for (int n = 0; n < 6; ++n) {
    int r = wn * 96 + n * 16 + (lane & 15);
    int sl = (lane >> 4) ^ ((r >> 1) & 3);
    offB[n] = r * 64 + sl * 16;
  }

  stage(0, 0);
  for (int tk = 0; tk < NTK; ++tk) {
    int cur = tk & 1;
    __syncthreads();               // drains vmcnt(0): staged tile ready
    if (tk + 1 < NTK) stage(tk + 1, cur ^ 1);
    bf16x8 af[2], bfr[6];
    #pragma unroll
    for (int m = 0; m < 2; ++m) af[m] = *(const bf16x8*)(As[cur] + offA[m]);
    #pragma unroll
    for (int n = 0; n < 6; ++n) bfr[n] = *(const bf16x8*)(Bs[cur] + offB[n]);
    #pragma unroll
    for (int m = 0; m < 2; ++m)
      #pragma unroll
      for (int n = 0; n < 6; ++n)
        acc[m][n] = __builtin_amdgcn_mfma_f32_16x16x32_bf16(af[m], bfr[n], acc[m][n], 0, 0, 0);
  }

  // epilogue: sum of squares over this block's 96-col slice, reduce 16 lanes,
  // atomicAdd into norm2[row]  (C/D layout: col=lane&15, row=(lane>>4)*4+reg)
  float ps[2][4];
  #pragma unroll
  for (int m = 0; m < 2; ++m)
    #pragma unroll
    for (int i = 0; i < 4; ++i) {
      float v = 0.f;
      #pragma unroll
      for (int n = 0; n < 6; ++n) { float x = acc[m][n][i]; v += x * x; }
      #pragma unroll
      for (int d = 1; d < 16; d <<= 1) v += __shfl_xor(v, d, 64);
      ps[m][i] = v;
    }
  if ((lane & 15) == 0) {
    int g = lane >> 4;
    #pragma unroll
    for (int m = 0; m < 2; ++m)
      #pragma unroll
      for (int i = 0; i < 4; ++i)
        atomicAdd(&norm2[tm * BM + wm * 32 + m * 16 + g * 4 + i], ps[m][i]);
  }
}

// ---------------- kernel C: cv = relu(sqrt(norm2)*scale); shapley ------------
__global__ __launch_bounds__(128) void kC(const char* __restrict__ ws,
                                          const float* __restrict__ scale,
                                          float* __restrict__ out) {
  const int b = blockIdx.x, n = threadIdx.x;
  const float* norm2 = (const float*)(ws + OFF_N2);
  const float* coefT = (const float*)(ws + OFF_COEF);
  __shared__ float cvs[32];
  if (n < KMC) {
    float nv = norm2[b * KMC + n];
    cvs[n] = fmaxf(sqrtf(fmaxf(nv, 0.f)) * scale[0], 0.f);
  } else if (n < 32) {
    cvs[n] = 0.f;
  }
  __syncthreads();
  float sum = 0.f;
  #pragma unroll
  for (int k = 0; k < KMC; ++k) sum += cvs[k] * coefT[n * 28 + k];
  out[b * NSP + n] = sum;
}

extern "C" void kernel_launch(void* const* d_in, const int* in_sizes, int n_in,
                              void* d_out, int out_size, void* d_ws, size_t ws_size,
                              hipStream_t stream) {
  const float* features   = (const float*)d_in[0];
  const int*   coalitions = (const int*)d_in[1];
  const float* wv         = (const float*)d_in[2];
  const float* scale      = (const float*)d_in[3];
  char* ws = (char*)d_ws;

  prep_kernel<<<202, 256, 0, stream>>>(wv, coalitions, ws);
  dim3 gaa(NB, 2);
  kA<<<gaa, 256, 0, stream>>>(features, (const __hip_bfloat16*)(ws + OFF_CB),
                              (__hip_bfloat16*)(ws + OFF_S));
  kB<<<400, 256, 0, stream>>>(ws);
  kC<<<NB, 128, 0, stream>>>(ws, scale, (float*)d_out);
}